// Round 3
// baseline (240.474 us; speedup 1.0000x reference)
//
#include <hip/hip_runtime.h>
#include <hip/hip_bf16.h>

// Problem constants (from reference):
//   streams: x250 (len 15000, step 4), x500 (len 30000, step 2), x1000 (len 60000, step 1)
//   L = max_len = 60000, D_MODEL = 256, KERNEL = 5, pad = 2
// Inputs: float32. Output buffer: float32 (harness compares both sides after
// bf16 truncation; threshold is 2% of ref max — generous).
// Output layout (flat, float32):
//   X: [3, 256, 60000]  = 46,080,000 elems
//   S: [2, 60000]       =    120,000 elems   (rows then cols)

#define L_OUT   60000
#define LEN0    15000
#define LEN1    30000
#define LEN2    60000
#define DMODEL  256
#define X_ELEMS (3 * DMODEL * L_OUT)

__device__ __forceinline__ float ld_or_zero(const float* __restrict__ x,
                                            int idx, int len) {
    return (idx >= 0 && idx < len) ? x[idx] : 0.0f;
}

__global__ __launch_bounds__(256) void conv_gather_kernel(
    const float* __restrict__ x250,
    const float* __restrict__ x500,
    const float* __restrict__ x1000,
    const float* __restrict__ W,   // [256, 1, 5]
    const float* __restrict__ b,   // [256]
    float* __restrict__ out)       // X region, fp32
{
    const int i  = blockIdx.z;              // stream
    const int c  = blockIdx.y;              // channel (wave-uniform -> scalar W/b loads)
    const int p0 = (blockIdx.x * 256 + threadIdx.x) * 4;
    if (p0 >= L_OUT) return;                // 59*256*4 = 60416 slots; tail returns

    const float w0 = W[c * 5 + 0];
    const float w1 = W[c * 5 + 1];
    const float w2 = W[c * 5 + 2];
    const float w3 = W[c * 5 + 3];
    const float w4 = W[c * 5 + 4];
    const float bias = b[c];

    float4 y;
    float yv[4];

    if (i == 0) {
        // step 4: only tap k=2 lands on a sample. Masked to 0 for p >= 15000.
#pragma unroll
        for (int j = 0; j < 4; ++j) {
            const int p = p0 + j;
            yv[j] = (p < LEN0) ? fmaf(w2, x250[p], bias) : 0.0f;
        }
    } else if (i == 1) {
        // step 2: taps k=0,2,4 -> x500[p-1], x500[p], x500[p+1]. Masked for p >= 30000.
#pragma unroll
        for (int j = 0; j < 4; ++j) {
            const int p = p0 + j;
            if (p < LEN1) {
                float acc = fmaf(w0, ld_or_zero(x500, p - 1, LEN1), bias);
                acc = fmaf(w2, x500[p], acc);
                acc = fmaf(w4, ld_or_zero(x500, p + 1, LEN1), acc);
                yv[j] = acc;
            } else {
                yv[j] = 0.0f;
            }
        }
    } else {
        // step 1: full 5-tap conv on x1000, 'same' zero padding.
#pragma unroll
        for (int j = 0; j < 4; ++j) {
            const int p = p0 + j;
            float acc = fmaf(w0, ld_or_zero(x1000, p - 2, LEN2), bias);
            acc = fmaf(w1, ld_or_zero(x1000, p - 1, LEN2), acc);
            acc = fmaf(w2, x1000[p], acc);
            acc = fmaf(w3, ld_or_zero(x1000, p + 1, LEN2), acc);
            acc = fmaf(w4, ld_or_zero(x1000, p + 2, LEN2), acc);
            yv[j] = acc;
        }
    }

    y.x = yv[0]; y.y = yv[1]; y.z = yv[2]; y.w = yv[3];
    // row offset = 60000*(i*256+c) floats; 60000 % 4 == 0 and p0 % 4 == 0 -> 16B aligned
    *(float4*)(out + (size_t)(i * DMODEL + c) * L_OUT + p0) = y;
}

__global__ __launch_bounds__(256) void s_kernel(float* __restrict__ out_s)
{
    const int v = blockIdx.x * 256 + threadIdx.x;
    if (v >= (2 * L_OUT) / 4) return;   // 30000 float4 stores
    const int t0 = v * 4;

    float4 o;
    float ov[4];
#pragma unroll
    for (int j = 0; j < 4; ++j) {
        const int t = t0 + j;
        float val;
        if (t < L_OUT) {
            // rows: 0 (t<15000), 1 (t<45000), 2
            val = (t < 15000) ? 0.0f : ((t < 45000) ? 1.0f : 2.0f);
        } else {
            // cols
            const int u = t - L_OUT;
            int iv;
            if (u < 15000)      iv = 4 * u;
            else if (u < 45000) iv = 2 * (u - 15000);
            else                iv = u - 45000;
            val = (float)iv;
        }
        ov[j] = val;
    }
    o.x = ov[0]; o.y = ov[1]; o.z = ov[2]; o.w = ov[3];
    *(float4*)(out_s + t0) = o;
}

extern "C" void kernel_launch(void* const* d_in, const int* in_sizes, int n_in,
                              void* d_out, int out_size, void* d_ws, size_t ws_size,
                              hipStream_t stream) {
    const float* x250  = (const float*)d_in[0];
    const float* x500  = (const float*)d_in[1];
    const float* x1000 = (const float*)d_in[2];
    const float* W     = (const float*)d_in[3];
    const float* b     = (const float*)d_in[4];
    float* out = (float*)d_out;

    // X: grid (ceil(15000/256)=59 position-chunks, 256 channels, 3 streams)
    dim3 grid_x(59, DMODEL, 3);
    conv_gather_kernel<<<grid_x, 256, 0, stream>>>(x250, x500, x1000, W, b, out);

    // S: 120000 fp32 elems = 30000 float4 stores
    s_kernel<<<(30000 + 255) / 256, 256, 0, stream>>>(out + X_ELEMS);
}

// Round 5
// 216.304 us; speedup vs baseline: 1.1117x; 1.1117x over previous
//
#include <hip/hip_runtime.h>
#include <hip/hip_bf16.h>

// streams: x250 (len 15000, step 4), x500 (len 30000, step 2), x1000 (len 60000, step 1)
// L = 60000, D_MODEL = 256, KERNEL = 5 (taps), pad = 2. Inputs fp32, output fp32.
// Output layout (flat fp32): X [3,256,60000] = 46,080,000 elems; S [2,60000] = 120,000.
// Conv collapses per stream (zero-insertion upsample):
//   i=0: y = b + w2*x250[p]                                  (p<15000)
//   i=1: y = b + w0*x500[p-1] + w2*x500[p] + w4*x500[p+1]    (p<30000)
//   i=2: full 5-tap on x1000                                 (p<60000)

#define L_OUT   60000
#define LEN0    15000
#define LEN1    30000
#define LEN2    60000
#define DMODEL  256
#define X_ELEMS (3 * DMODEL * L_OUT)

typedef float float4v __attribute__((ext_vector_type(4)));  // clang vector: nt-store OK

__device__ __forceinline__ float ld_or_zero(const float* __restrict__ x,
                                            int idx, int len) {
    return (idx >= 0 && idx < len) ? x[idx] : 0.0f;
}

__device__ __forceinline__ void st_nt4(float* p, float a, float b, float c, float d) {
    float4v v; v.x = a; v.y = b; v.z = c; v.w = d;
    __builtin_nontemporal_store(v, (float4v*)p);
}

// 8 positions per thread, two nontemporal float4 stores.
// grid: (30 chunks of 2048 positions, 256 channels, 3 streams), 256 threads.
__global__ __launch_bounds__(256) void conv_gather_kernel(
    const float* __restrict__ x250,
    const float* __restrict__ x500,
    const float* __restrict__ x1000,
    const float* __restrict__ W,   // [256,1,5]
    const float* __restrict__ b,   // [256]
    float* __restrict__ out)
{
    const int i  = blockIdx.z;
    const int c  = blockIdx.y;
    const int p0 = (blockIdx.x * 256 + threadIdx.x) * 8;
    if (p0 >= L_OUT) return;       // 30*256*8 = 61440 slots, tail idles

    const float w0 = W[c * 5 + 0];
    const float w1 = W[c * 5 + 1];
    const float w2 = W[c * 5 + 2];
    const float w3 = W[c * 5 + 3];
    const float w4 = W[c * 5 + 4];
    const float bias = b[c];

    float y[8];

    if (i == 0) {
        if (p0 + 8 <= LEN0) {                 // interior fast path
#pragma unroll
            for (int j = 0; j < 8; ++j) y[j] = fmaf(w2, x250[p0 + j], bias);
        } else {
#pragma unroll
            for (int j = 0; j < 8; ++j) {
                const int p = p0 + j;
                y[j] = (p < LEN0) ? fmaf(w2, x250[p], bias) : 0.0f;
            }
        }
    } else if (i == 1) {
        if (p0 >= 1 && p0 + 9 <= LEN1) {      // interior fast path (needs p0-1 .. p0+8)
#pragma unroll
            for (int j = 0; j < 8; ++j) {
                const int p = p0 + j;
                float acc = fmaf(w0, x500[p - 1], bias);
                acc = fmaf(w2, x500[p], acc);
                acc = fmaf(w4, x500[p + 1], acc);
                y[j] = acc;
            }
        } else {
#pragma unroll
            for (int j = 0; j < 8; ++j) {
                const int p = p0 + j;
                if (p < LEN1) {
                    float acc = fmaf(w0, ld_or_zero(x500, p - 1, LEN1), bias);
                    acc = fmaf(w2, x500[p], acc);
                    acc = fmaf(w4, ld_or_zero(x500, p + 1, LEN1), acc);
                    y[j] = acc;
                } else {
                    y[j] = 0.0f;
                }
            }
        }
    } else {
        if (p0 >= 2 && p0 + 10 <= LEN2) {     // interior fast path (needs p0-2 .. p0+9)
#pragma unroll
            for (int j = 0; j < 8; ++j) {
                const int p = p0 + j;
                float acc = fmaf(w0, x1000[p - 2], bias);
                acc = fmaf(w1, x1000[p - 1], acc);
                acc = fmaf(w2, x1000[p], acc);
                acc = fmaf(w3, x1000[p + 1], acc);
                acc = fmaf(w4, x1000[p + 2], acc);
                y[j] = acc;
            }
        } else {
#pragma unroll
            for (int j = 0; j < 8; ++j) {
                const int p = p0 + j;
                float acc = fmaf(w0, ld_or_zero(x1000, p - 2, LEN2), bias);
                acc = fmaf(w1, ld_or_zero(x1000, p - 1, LEN2), acc);
                acc = fmaf(w2, x1000[p], acc);
                acc = fmaf(w3, ld_or_zero(x1000, p + 1, LEN2), acc);
                acc = fmaf(w4, ld_or_zero(x1000, p + 2, LEN2), acc);
                y[j] = acc;
            }
        }
    }

    float* dst = out + (size_t)(i * DMODEL + c) * L_OUT + p0;  // 16B aligned
    st_nt4(dst,     y[0], y[1], y[2], y[3]);
    st_nt4(dst + 4, y[4], y[5], y[6], y[7]);
}

__global__ __launch_bounds__(256) void s_kernel(float* __restrict__ out_s)
{
    const int v = blockIdx.x * 256 + threadIdx.x;
    if (v >= (2 * L_OUT) / 4) return;   // 30000 float4 stores
    const int t0 = v * 4;

    float ov[4];
#pragma unroll
    for (int j = 0; j < 4; ++j) {
        const int t = t0 + j;
        float val;
        if (t < L_OUT) {
            val = (t < 15000) ? 0.0f : ((t < 45000) ? 1.0f : 2.0f);   // rows
        } else {
            const int u = t - L_OUT;                                  // cols
            int iv;
            if (u < 15000)      iv = 4 * u;
            else if (u < 45000) iv = 2 * (u - 15000);
            else                iv = u - 45000;
            val = (float)iv;
        }
        ov[j] = val;
    }
    st_nt4(out_s + t0, ov[0], ov[1], ov[2], ov[3]);
}

extern "C" void kernel_launch(void* const* d_in, const int* in_sizes, int n_in,
                              void* d_out, int out_size, void* d_ws, size_t ws_size,
                              hipStream_t stream) {
    const float* x250  = (const float*)d_in[0];
    const float* x500  = (const float*)d_in[1];
    const float* x1000 = (const float*)d_in[2];
    const float* W     = (const float*)d_in[3];
    const float* b     = (const float*)d_in[4];
    float* out = (float*)d_out;

    dim3 grid_x(30, DMODEL, 3);   // 8 positions/thread
    conv_gather_kernel<<<grid_x, 256, 0, stream>>>(x250, x500, x1000, W, b, out);

    s_kernel<<<(30000 + 255) / 256, 256, 0, stream>>>(out + X_ELEMS);
}